// Round 10
// baseline (246.337 us; speedup 1.0000x reference)
//
#include <hip/hip_runtime.h>

typedef _Float16 f16;
typedef f16 f16x8 __attribute__((ext_vector_type(8)));
typedef f16 f16x4 __attribute__((ext_vector_type(4)));
typedef short s16x8 __attribute__((ext_vector_type(8)));
typedef short s16x4 __attribute__((ext_vector_type(4)));
typedef float f32x4 __attribute__((ext_vector_type(4)));

#define MFMA16(a,b,c)  __builtin_amdgcn_mfma_f32_16x16x32_f16(a,b,c,0,0,0)
#define MFMAB16(a,b,c) __builtin_amdgcn_mfma_f32_16x16x32_bf16(a,b,c,0,0,0)

static constexpr int Bn = 8, Qn = 2048, Kn = 2048, Hn = 512;
static constexpr int Mn = Bn * Qn;           // 16384 flat rows

typedef __attribute__((address_space(1))) const unsigned int as1_uint;
typedef __attribute__((address_space(3))) unsigned int as3_uint;

__device__ __forceinline__ void gl_lds16(const void* g, void* l) {
    __builtin_amdgcn_global_load_lds((as1_uint*)g, (as3_uint*)l, 16, 0, 0);
}

__device__ __forceinline__ short bf16r(float x) {
    unsigned u = __builtin_bit_cast(unsigned, x);
    u += 0x7fffu + ((u >> 16) & 1u);
    return (short)(u >> 16);
}

// swizzle granule: 2-way (free) bank aliasing for ds_read_b128 column reads
__device__ __forceinline__ int swz(int row) { return (row >> 1) & 3; }

// ---------------------------------------------------------------------------
// prep_all: blocks 0..7 compact_mask; 8..1031 weight split/transpose;
// 1032 bias vectors.
// ---------------------------------------------------------------------------
__global__ __launch_bounds__(256) void prep_all(
    const int* __restrict__ mask, const float* __restrict__ Wk,
    const float* __restrict__ Wo, const float* __restrict__ bq,
    const float* __restrict__ bv, const float* __restrict__ bo,
    int* __restrict__ cidx, int* __restrict__ cnt,
    f16* __restrict__ Wk_h, f16* __restrict__ Wk_l, short* __restrict__ Wot,
    float* __restrict__ wvec, float* __restrict__ cvec)
{
    const int bid = blockIdx.x, t = threadIdx.x;
    if (bid < 8) {
        __shared__ int sums[256];
        int b = bid;
        int base = b * Kn + t * 8;
        int mv[8]; int s = 0;
        #pragma unroll
        for (int i = 0; i < 8; ++i) { mv[i] = (mask[base + i] == 0); s += mv[i]; }
        sums[t] = s;
        __syncthreads();
        for (int off = 1; off < 256; off <<= 1) {
            int v = (t >= off) ? sums[t - off] : 0;
            __syncthreads();
            sums[t] += v;
            __syncthreads();
        }
        int pos = (t > 0 ? sums[t - 1] : 0);
        #pragma unroll
        for (int i = 0; i < 8; ++i)
            if (mv[i]) cidx[b * Kn + pos++] = t * 8 + i;
        if (t == 255) {
            int total = sums[255];
            if (total == 0) { cidx[b * Kn] = 0; total = 1; }
            cnt[b] = total;
        }
    } else if (bid < 1032) {
        int e = (bid - 8) * 256 + t;
        float v = Wk[e] * 512.0f;
        f16 h = (f16)v;
        Wk_h[e] = h; Wk_l[e] = (f16)((v - (float)h) * 2048.0f);
        int r = e >> 9, c = e & 511;
        Wot[c * 512 + r] = bf16r(Wo[e]);
    } else {
        #pragma unroll
        for (int i = 0; i < 2; ++i) {
            int tt = t + i * 256;
            float s = 0.f;
            for (int n = 0; n < 512; n += 4) {
                f32x4 a = *(const f32x4*)(Wk + (size_t)tt * 512 + n);
                f32x4 q = *(const f32x4*)(bq + n);
                s += a[0]*q[0] + a[1]*q[1] + a[2]*q[2] + a[3]*q[3];
            }
            wvec[tt] = s * (1.0f / 512.0f);
            float s2 = 0.f;
            for (int h = 0; h < 512; ++h) s2 += bv[h] * Wo[h * 512 + tt];
            cvec[tt] = s2 + bo[tt];
        }
    }
}

// ---------------------------------------------------------------------------
// gemm_split<PREP>: fp16x2 3-product GEMM_BT, 64m x 128n tile, 48KB LDS dbuf.
//  PREP=1: Mt = A.Bt (=M x512), split out TRANSPOSED [n][m]
// ---------------------------------------------------------------------------
template<int PREP>
__global__ __launch_bounds__(256) void gemm_split(
    const float* __restrict__ Af,
    const f16* __restrict__ Bh_g, const f16* __restrict__ Bl_g,
    f16* __restrict__ Oh, f16* __restrict__ Ol)
{
    __shared__ __align__(16) f16 Ah[2][2048], Al[2][2048], Bh[2][4096], Bl[2][4096];
    const int tid = threadIdx.x, lane = tid & 63, wid = tid >> 6;
    const int l15 = lane & 15, lg = lane >> 4;
    const int m0 = blockIdx.x * 64, n0 = blockIdx.y * 128;
    const int srow = lane >> 2, sg = lane & 3;
    const int ar0 = tid >> 3, ac0 = (tid & 7) * 4;

    auto stageB = [&](int buf, int ks) {
        const int k0 = ks << 5;
        #pragma unroll
        for (int h = 0; h < 2; ++h) {
            int s = wid + h * 4;
            int row = s * 16 + srow;
            int goff = k0 + ((sg ^ swz(row)) << 3);
            gl_lds16(Bh_g + (size_t)(n0 + row) * Hn + goff, &Bh[buf][s * 512]);
            gl_lds16(Bl_g + (size_t)(n0 + row) * Hn + goff, &Bl[buf][s * 512]);
        }
    };
    auto writeA = [&](int buf, const f32x4* av) {
        #pragma unroll
        for (int rr = 0; rr < 2; ++rr) {
            int row = ar0 + rr * 32;
            f16x4 oh, ol;
            #pragma unroll
            for (int j = 0; j < 4; ++j) {
                f16 hh = (f16)av[rr][j];
                oh[j] = hh;
                ol[j] = (f16)((av[rr][j] - (float)hh) * 2048.0f);
            }
            int off = row * 32 + (((ac0 >> 3) ^ swz(row)) << 3) + (ac0 & 7);
            *(f16x4*)&Ah[buf][off] = oh;
            *(f16x4*)&Al[buf][off] = ol;
        }
    };

    const float* aSrc[2];
    #pragma unroll
    for (int rr = 0; rr < 2; ++rr)
        aSrc[rr] = Af + (size_t)(m0 + ar0 + rr * 32) * Hn;

    f32x4 a0[4][2] = {}, a1[4][2] = {};
    {
        f32x4 av[2];
        #pragma unroll
        for (int rr = 0; rr < 2; ++rr) av[rr] = *(const f32x4*)(aSrc[rr] + ac0);
        stageB(0, 0);
        writeA(0, av);
    }
    __syncthreads();
    #pragma unroll 1
    for (int ks = 0; ks < 16; ++ks) {
        const int cur = ks & 1, nxt = cur ^ 1;
        f32x4 av[2];
        if (ks < 15) {
            const int k1 = (ks + 1) << 5;
            #pragma unroll
            for (int rr = 0; rr < 2; ++rr) av[rr] = *(const f32x4*)(aSrc[rr] + k1 + ac0);
            stageB(nxt, ks + 1);
        }
        f16x8 fbh[2], fbl[2];
        #pragma unroll
        for (int fj = 0; fj < 2; ++fj) {
            int row = wid * 32 + fj * 16 + l15;
            int off = row * 32 + ((lg ^ swz(row)) << 3);
            fbh[fj] = *(f16x8*)&Bh[cur][off];
            fbl[fj] = *(f16x8*)&Bl[cur][off];
        }
        #pragma unroll
        for (int fi = 0; fi < 4; ++fi) {
            int row = fi * 16 + l15;
            int off = row * 32 + ((lg ^ swz(row)) << 3);
            f16x8 fah = *(f16x8*)&Ah[cur][off];
            f16x8 fal = *(f16x8*)&Al[cur][off];
            #pragma unroll
            for (int fj = 0; fj < 2; ++fj) {
                a0[fi][fj] = MFMA16(fah, fbh[fj], a0[fi][fj]);
                a1[fi][fj] = MFMA16(fah, fbl[fj], a1[fi][fj]);
                a1[fi][fj] = MFMA16(fal, fbh[fj], a1[fi][fj]);
            }
        }
        if (ks < 15) writeA(nxt, av);
        __syncthreads();
    }
    #pragma unroll
    for (int fi = 0; fi < 4; ++fi)
    #pragma unroll
    for (int fj = 0; fj < 2; ++fj)
    #pragma unroll
    for (int j = 0; j < 4; ++j) {
        int m = m0 + fi * 16 + lg * 4 + j;
        int n = n0 + wid * 32 + fj * 16 + l15;
        float v = a0[fi][fj][j] + a1[fi][fj][j] * (1.0f / 2048.0f);
        if (PREP == 0) v *= (1.0f / 512.0f);
        f16 h = (f16)v;
        f16 lo = (f16)((v - (float)h) * 2048.0f);
        size_t o = PREP ? ((size_t)n * Hn + m) : ((size_t)m * Hn + n);
        Oh[o] = h; Ol[o] = lo;
    }
}

// ---------------------------------------------------------------------------
// gemm_bfk0: NtB prep — A=Wv rows, out bf16 TRANSPOSED [n][m], no bias.
// ---------------------------------------------------------------------------
__global__ __launch_bounds__(256) void gemm_bfk0(
    const float* __restrict__ Af, const short* __restrict__ Bt,
    short* __restrict__ Out)
{
    __shared__ __align__(16) short As[2][2048], Bs[2][4096];
    const int tid = threadIdx.x, lane = tid & 63, wid = tid >> 6;
    const int l15 = lane & 15, lg = lane >> 4;
    const int m0 = blockIdx.x * 64, n0 = blockIdx.y * 128;
    const int srow = lane >> 2, sg = lane & 3;
    const int ar0 = tid >> 3, ac0 = (tid & 7) * 4;

    const float* aSrc[2];
    #pragma unroll
    for (int rr = 0; rr < 2; ++rr)
        aSrc[rr] = Af + (size_t)(m0 + ar0 + rr * 32) * Hn;

    auto stageB = [&](int buf, int ks) {
        const int k0 = ks << 5;
        #pragma unroll
        for (int h = 0; h < 2; ++h) {
            int s = wid + h * 4;
            int row = s * 16 + srow;
            int goff = k0 + ((sg ^ swz(row)) << 3);
            gl_lds16(Bt + (size_t)(n0 + row) * Hn + goff, &Bs[buf][s * 512]);
        }
    };
    auto writeA = [&](int buf, const f32x4* av) {
        #pragma unroll
        for (int rr = 0; rr < 2; ++rr) {
            int row = ar0 + rr * 32;
            s16x4 o;
            #pragma unroll
            for (int j = 0; j < 4; ++j) o[j] = bf16r(av[rr][j]);
            int off = row * 32 + (((ac0 >> 3) ^ swz(row)) << 3) + (ac0 & 7);
            *(s16x4*)&As[buf][off] = o;
        }
    };

    f32x4 acc[4][2] = {};
    {
        f32x4 av[2];
        #pragma unroll
        for (int rr = 0; rr < 2; ++rr) av[rr] = *(const f32x4*)(aSrc[rr] + ac0);
        stageB(0, 0);
        writeA(0, av);
    }
    __syncthreads();
    #pragma unroll 1
    for (int ks = 0; ks < 16; ++ks) {
        const int cur = ks & 1, nxt = cur ^ 1;
        f32x4 av[2];
        if (ks < 15) {
            const int k1 = (ks + 1) << 5;
            #pragma unroll
            for (int rr = 0; rr < 2; ++rr) av[rr] = *(const f32x4*)(aSrc[rr] + k1 + ac0);
            stageB(nxt, ks + 1);
        }
        s16x8 fb[2];
        #pragma unroll
        for (int fj = 0; fj < 2; ++fj) {
            int row = wid * 32 + fj * 16 + l15;
            fb[fj] = *(s16x8*)&Bs[cur][row * 32 + ((lg ^ swz(row)) << 3)];
        }
        #pragma unroll
        for (int fi = 0; fi < 4; ++fi) {
            int row = fi * 16 + l15;
            s16x8 fa = *(s16x8*)&As[cur][row * 32 + ((lg ^ swz(row)) << 3)];
            #pragma unroll
            for (int fj = 0; fj < 2; ++fj)
                acc[fi][fj] = MFMAB16(fa, fb[fj], acc[fi][fj]);
        }
        if (ks < 15) writeA(nxt, av);
        __syncthreads();
    }
    #pragma unroll
    for (int fi = 0; fi < 4; ++fi)
    #pragma unroll
    for (int fj = 0; fj < 2; ++fj)
    #pragma unroll
    for (int j = 0; j < 4; ++j) {
        int m = m0 + fi * 16 + lg * 4 + j;
        int n = n0 + wid * 32 + fj * 16 + l15;
        Out[(size_t)n * Hn + m] = bf16r(acc[fi][fj][j]);
    }
}

// ---------------------------------------------------------------------------
// qm_kconv: blocks 0..1023 = qM split GEMM (query.Mt, /512, split out);
// blocks 1024..5119 = kconv (raw-k gather -> f16 hi + beta).
// ---------------------------------------------------------------------------
__global__ __launch_bounds__(256) void qm_kconv(
    const float* __restrict__ query,
    const f16* __restrict__ Mt_h, const f16* __restrict__ Mt_l,
    f16* __restrict__ qM_h, f16* __restrict__ qM_l,
    const float* __restrict__ key_, const int* __restrict__ cidx,
    const int* __restrict__ cnt, const float* __restrict__ wvec,
    f16* __restrict__ Kc_h, float* __restrict__ beta)
{
    __shared__ __align__(16) f16 smem[2][2048 + 2048 + 4096 + 4096];
    const int bid = blockIdx.x;
    const int tid = threadIdx.x, lane = tid & 63, wid = tid >> 6;
    if (bid < 1024) {
        f16 (*Ah)[2048+2048+4096+4096] = smem;
        #define AH(b,i) Ah[b][i]
        #define AL(b,i) Ah[b][2048 + (i)]
        #define BH(b,i) Ah[b][4096 + (i)]
        #define BL(b,i) Ah[b][8192 + (i)]
        const int l15 = lane & 15, lg = lane >> 4;
        const int m0 = (bid & 255) * 64, n0 = (bid >> 8) * 128;
        const int srow = lane >> 2, sg = lane & 3;
        const int ar0 = tid >> 3, ac0 = (tid & 7) * 4;

        auto stageB = [&](int buf, int ks) {
            const int k0 = ks << 5;
            #pragma unroll
            for (int h = 0; h < 2; ++h) {
                int s = wid + h * 4;
                int row = s * 16 + srow;
                int goff = k0 + ((sg ^ swz(row)) << 3);
                gl_lds16(Mt_h + (size_t)(n0 + row) * Hn + goff, &BH(buf, s * 512));
                gl_lds16(Mt_l + (size_t)(n0 + row) * Hn + goff, &BL(buf, s * 512));
            }
        };
        auto writeA = [&](int buf, const f32x4* av) {
            #pragma unroll
            for (int rr = 0; rr < 2; ++rr) {
                int row = ar0 + rr * 32;
                f16x4 oh, ol;
                #pragma unroll
                for (int j = 0; j < 4; ++j) {
                    f16 hh = (f16)av[rr][j];
                    oh[j] = hh;
                    ol[j] = (f16)((av[rr][j] - (float)hh) * 2048.0f);
                }
                int off = row * 32 + (((ac0 >> 3) ^ swz(row)) << 3) + (ac0 & 7);
                *(f16x4*)&AH(buf, off) = oh;
                *(f16x4*)&AL(buf, off) = ol;
            }
        };

        const float* aSrc[2];
        #pragma unroll
        for (int rr = 0; rr < 2; ++rr)
            aSrc[rr] = query + (size_t)(m0 + ar0 + rr * 32) * Hn;

        f32x4 a0[4][2] = {}, a1[4][2] = {};
        {
            f32x4 av[2];
            #pragma unroll
            for (int rr = 0; rr < 2; ++rr) av[rr] = *(const f32x4*)(aSrc[rr] + ac0);
            stageB(0, 0);
            writeA(0, av);
        }
        __syncthreads();
        #pragma unroll 1
        for (int ks = 0; ks < 16; ++ks) {
            const int cur = ks & 1, nxt = cur ^ 1;
            f32x4 av[2];
            if (ks < 15) {
                const int k1 = (ks + 1) << 5;
                #pragma unroll
                for (int rr = 0; rr < 2; ++rr) av[rr] = *(const f32x4*)(aSrc[rr] + k1 + ac0);
                stageB(nxt, ks + 1);
            }
            f16x8 fbh[2], fbl[2];
            #pragma unroll
            for (int fj = 0; fj < 2; ++fj) {
                int row = wid * 32 + fj * 16 + l15;
                int off = row * 32 + ((lg ^ swz(row)) << 3);
                fbh[fj] = *(f16x8*)&BH(cur, off);
                fbl[fj] = *(f16x8*)&BL(cur, off);
            }
            #pragma unroll
            for (int fi = 0; fi < 4; ++fi) {
                int row = fi * 16 + l15;
                int off = row * 32 + ((lg ^ swz(row)) << 3);
                f16x8 fah = *(f16x8*)&AH(cur, off);
                f16x8 fal = *(f16x8*)&AL(cur, off);
                #pragma unroll
                for (int fj = 0; fj < 2; ++fj) {
                    a0[fi][fj] = MFMA16(fah, fbh[fj], a0[fi][fj]);
                    a1[fi][fj] = MFMA16(fah, fbl[fj], a1[fi][fj]);
                    a1[fi][fj] = MFMA16(fal, fbh[fj], a1[fi][fj]);
                }
            }
            if (ks < 15) writeA(nxt, av);
            __syncthreads();
        }
        #pragma unroll
        for (int fi = 0; fi < 4; ++fi)
        #pragma unroll
        for (int fj = 0; fj < 2; ++fj)
        #pragma unroll
        for (int j = 0; j < 4; ++j) {
            int m = m0 + fi * 16 + lg * 4 + j;
            int n = n0 + wid * 32 + fj * 16 + l15;
            float v = (a0[fi][fj][j] + a1[fi][fj][j] * (1.0f / 2048.0f)) * (1.0f / 512.0f);
            f16 h = (f16)v;
            qM_h[(size_t)m * Hn + n] = h;
            qM_l[(size_t)m * Hn + n] = (f16)((v - (float)h) * 2048.0f);
        }
        #undef AH
        #undef AL
        #undef BH
        #undef BL
    } else {
        int kb = bid - 1024;                 // [0, 4096)
        int b = kb >> 9;
        int j = (kb & 511) * 4 + wid;
        int cn = cnt[b];
        if (j >= cn) return;
        const float* src = key_ + (size_t)(b * Kn + cidx[b * Kn + j]) * Hn;
        size_t dst = (size_t)(b * Kn + j) * Hn;
        float s = 0.f;
        #pragma unroll
        for (int i = 0; i < 2; ++i) {
            int c0 = lane * 8 + i * 4;
            f32x4 v = *(const f32x4*)(src + c0);
            f32x4 w = *(const f32x4*)(wvec + c0);
            f16x4 oh;
            #pragma unroll
            for (int e = 0; e < 4; ++e) {
                oh[e] = (f16)v[e];
                s += v[e] * w[e];
            }
            *(f16x4*)(Kc_h + dst + c0) = oh;
        }
        #pragma unroll
        for (int sm = 1; sm < 64; sm <<= 1) s += __shfl_xor(s, sm, 64);
        if (lane == 0) beta[b * Kn + j] = s;
    }
}

// ---------------------------------------------------------------------------
// energy_approx: hi*hi-only f16 GEMM, 128q x 128k tile, 2x2 waves, 32KB LDS.
// Writes approx energies (f16, +beta, NEGI OOB) AND per-(row,chunk) top-1.
// ---------------------------------------------------------------------------
__global__ __launch_bounds__(256) void energy_approx(
    const f16* __restrict__ Qh, const f16* __restrict__ Kh,
    const float* __restrict__ beta, const int* __restrict__ cnt,
    f16* __restrict__ approxE, float* __restrict__ pval, int* __restrict__ pidx)
{
    __shared__ __align__(16) f16 Ah[2][4096], Bh[2][4096];
    const int tid = threadIdx.x, lane = tid & 63, wid = tid >> 6;
    const int wr = wid >> 1, wc = wid & 1, l15 = lane & 15, lg = lane >> 4;
    const int qt = blockIdx.x, kc = blockIdx.y, b = blockIdx.z;
    const int cn = cnt[b];
    const int kbase = kc << 7;
    if (kbase >= cn) return;
    const int m0 = b * Qn + qt * 128;
    const int kr0 = b * Kn + kbase;
    const int srow = lane >> 2, sg = lane & 3;
    const float NEGINF = -__builtin_inff();

    auto stage = [&](int buf, int ks) {
        const int k0 = ks << 5;
        #pragma unroll
        for (int h = 0; h < 2; ++h) {
            int s = wid + h * 4;
            int row = s * 16 + srow;
            int goff = k0 + ((sg ^ swz(row)) << 3);
            gl_lds16(Qh + (size_t)(m0 + row) * Hn + goff, &Ah[buf][s * 512]);
            gl_lds16(Kh + (size_t)(kr0 + row) * Hn + goff, &Bh[buf][s * 512]);
        }
    };

    f32x4 acc[4][4] = {};
    stage(0, 0);
    __syncthreads();
    #pragma unroll 1
    for (int ks = 0; ks < 16; ++ks) {
        const int cur = ks & 1;
        if (ks < 15) stage(cur ^ 1, ks + 1);
        f16x8 fb[4];
        #pragma unroll
        for (int fj = 0; fj < 4; ++fj) {
            int row = wc * 64 + fj * 16 + l15;
            fb[fj] = *(f16x8*)&Bh[cur][row * 32 + ((lg ^ swz(row)) << 3)];
        }
        #pragma unroll
        for (int fi = 0; fi < 4; ++fi) {
            int row = wr * 64 + fi * 16 + l15;
            f16x8 fa = *(f16x8*)&Ah[cur][row * 32 + ((lg ^ swz(row)) << 3)];
            #pragma unroll
            for (int fj = 0; fj < 4; ++fj)
                acc[fi][fj] = MFMA16(fa, fb[fj], acc[fi][fj]);
        }
        __syncthreads();
    }
    const f16 NEGI = (f16)NEGINF;
    float bet[4]; int valid[4];
    #pragma unroll
    for (int fj = 0; fj < 4; ++fj) {
        int lc = wc * 64 + fj * 16 + l15;
        valid[fj] = (kbase + lc < cn);
        bet[fj] = valid[fj] ? beta[b * Kn + kbase + lc] : 0.0f;
    }
    // reuse LDS (K-loop done): cross-wave reduction scratch
    float (*bwv)[128] = (float(*)[128])&Ah[0][0];   // [2][128]
    int   (*bwi)[128] = (int(*)[128])&Ah[1][0];
    #pragma unroll
    for (int fi = 0; fi < 4; ++fi)
    #pragma unroll
    for (int j = 0; j < 4; ++j) {
        float bv = NEGINF; int bc = 0x7fffffff;
        #pragma unroll
        for (int fj = 0; fj < 4; ++fj) {
            int lc = wc * 64 + fj * 16 + l15;
            float v = valid[fj] ? (acc[fi][fj][j] + bet[fj]) : NEGINF;
            int row = wr * 64 + fi * 16 + lg * 4 + j;
            approxE[(size_t)(m0 + row) * Kn + kbase + lc] = valid[fj] ? (f16)v : NEGI;
            if (v > bv || (v == bv && lc < bc)) { bv = v; bc = lc; }
        }
        #pragma unroll
        for (int sm = 1; sm < 16; sm <<= 1) {
            float ov = __shfl_xor(bv, sm, 64);
            int   oc = __shfl_xor(bc, sm, 64);
            if (ov > bv || (ov == bv && oc < bc)) { bv = ov; bc = oc; }
        }
        if (l15 == 0) {
            int row = wr * 64 + fi * 16 + lg * 4 + j;
            bwv[wc][row] = bv; bwi[wc][row] = bc;
        }
    }
    __syncthreads();
    if (tid < 128) {
        float v0 = bwv[0][tid], v1 = bwv[1][tid];
        int   i0 = bwi[0][tid], i1 = bwi[1][tid];
        float v; int i;
        if (v0 > v1 || (v0 == v1 && i0 < i1)) { v = v0; i = i0; } else { v = v1; i = i1; }
        int m = m0 + tid;
        pval[m * 16 + kc] = v;
        pidx[m * 16 + kc] = kbase + i;
    }
}

// ---------------------------------------------------------------------------
// refine: one wave per q-row. Chunk stats -> global max + window; scan only
// qualifying chunks in apxE; exact f32 dots only when >1 candidate.
// ---------------------------------------------------------------------------
__global__ __launch_bounds__(256) void refine(
    const f16* __restrict__ apxE, const float* __restrict__ pval,
    const int* __restrict__ pidx,
    const f16* __restrict__ qMh, const f16* __restrict__ qMl,
    const float* __restrict__ key_, const float* __restrict__ beta,
    const int* __restrict__ cidx, const int* __restrict__ cnt,
    int* __restrict__ idxArr)
{
    const int wid = threadIdx.x >> 6, lane = threadIdx.x & 63;
    const int m = blockIdx.x * 4 + wid;
    const int b = m >> 11;
    const int cn = cnt[b];
    const int nch = (cn + 127) >> 7;
    const float NEGINF = -__builtin_inff();

    float chv = (lane < nch) ? pval[m * 16 + lane] : NEGINF;
    int   chi = (lane < nch) ? pidx[m * 16 + lane] : 0x7fffffff;
    float gv = chv; int gi = chi;
    #pragma unroll
    for (int sm = 1; sm < 64; sm <<= 1) {
        float ov = __shfl_xor(gv, sm, 64);
        int   oc = __shfl_xor(gi, sm, 64);
        if (ov > gv || (ov == gv && oc < gi)) { gv = ov; gi = oc; }
    }
    const float thr = gv - 1.0f;

    int ncand = 0;
    for (int c = 0; c < nch; ++c) {
        float cmax = __shfl(chv, c, 64);
        if (cmax < thr) continue;
        const f16* ap = apxE + (size_t)m * Kn + c * 128 + lane * 2;
        ncand += __popcll(__ballot((float)ap[0] >= thr));
        ncand += __popcll(__ballot((float)ap[1] >= thr));
    }
    if (ncand == 1) {
        if (lane == 0) idxArr[m] = cidx[b * Kn + gi];
        return;
    }
    // exact path
    float q8[8];
    {
        f16x8 qh = *(const f16x8*)(qMh + (size_t)m * Hn + lane * 8);
        f16x8 ql = *(const f16x8*)(qMl + (size_t)m * Hn + lane * 8);
        #pragma unroll
        for (int e = 0; e < 8; ++e)
            q8[e] = (float)qh[e] + (float)ql[e] * (1.0f / 2048.0f);
    }
    float bestV = NEGINF; int bestOrig = 0x7fffffff;
    for (int c = 0; c < nch; ++c) {
        float cmax = __shfl(chv, c, 64);
        if (cmax < thr) continue;
        const f16* ap = apxE + (size_t)m * Kn + c * 128 + lane * 2;
        unsigned long long bb[2];
        bb[0] = __ballot((float)ap[0] >= thr);
        bb[1] = __ballot((float)ap[1] >= thr);
        #pragma unroll
        for (int p = 0; p < 2; ++p) {
            unsigned long long mb = bb[p];
            while (mb) {
                int L = __builtin_ctzll(mb);
                mb &= mb - 1;
                int j = c * 128 + L * 2 + p;
                int orig = cidx[b * Kn + j];
                const float* kr = key_ + ((size_t)(b * Kn + orig)) * Hn + lane * 8;
                float d = 0.f;
                #pragma unroll
                for (int e = 0; e < 8; ++e) d += q8[e] * kr[e];
                #pragma unroll
                for (int sm = 1; sm < 64; sm <<= 1) d += __shfl_xor(d, sm, 64);
                d += beta[b * Kn + j];
                if (d > bestV || (d == bestV && orig < bestOrig)) { bestV = d; bestOrig = orig; }
            }
        }
    }
    if (lane == 0) idxArr[m] = bestOrig;
}

// ---------------------------------------------------------------------------
// tail_fused: blocks 0..1023 = res GEMM (value[argmax].NtB + cvec, f32 out);
// blocks 1024.. = score one-hot rows (erases all scratch in score region).
// ---------------------------------------------------------------------------
__global__ __launch_bounds__(256) void tail_fused(
    const float* __restrict__ value, const short* __restrict__ NtB,
    const float* __restrict__ cvec, const int* __restrict__ idxArr,
    float* __restrict__ res, float* __restrict__ score)
{
    __shared__ __align__(16) short As[2][2048], Bs[2][4096];
    const int bid = blockIdx.x;
    const int tid = threadIdx.x, lane = tid & 63, wid = tid >> 6;
    if (bid >= 1024) {
        int m = bid - 1024;
        int c = idxArr[m];
        float* row = score + (size_t)m * Kn;
        #pragma unroll
        for (int i = 0; i < 2; ++i) {
            int v = tid + i * 256;
            f32x4 val = {0.f, 0.f, 0.f, 0.f};
            if ((c >> 2) == v) val[c & 3] = 1.0f;
            *(f32x4*)(row + v * 4) = val;
        }
        return;
    }
    const int l15 = lane & 15, lg = lane >> 4;
    const int m0 = (bid & 255) * 64, n0 = (bid >> 8) * 128;
    const int srow = lane >> 2, sg = lane & 3;
    const int ar0 = tid >> 3, ac0 = (tid & 7) * 4;

    const float* aSrc[2];
    #pragma unroll
    for (int rr = 0; rr < 2; ++rr) {
        int row = ar0 + rr * 32;
        int bb = m0 >> 11;
        aSrc[rr] = value + (size_t)(bb * Kn + idxArr[m0 + row]) * Hn;
    }

    auto stageB = [&](int buf, int ks) {
        const int k0 = ks << 5;
        #pragma unroll
        for (int h = 0; h < 2; ++h) {
            int s = wid + h * 4;
            int row = s * 16 + srow;
            int goff = k0 + ((sg ^ swz(row)) << 3);
            gl_lds16(NtB + (size_t)(n0 + row) * Hn + goff, &Bs[buf][s * 512]);
        }
    };
    auto writeA = [&](int buf, const f32x4* av) {
        #pragma unroll
        for (int rr = 0; rr < 2; ++rr) {
            int row = ar0 + rr * 32;
            s16x4 o;
            #pragma unroll
            for (int j = 0; j < 4; ++j) o[j] = bf16r(av[rr][j]);
            int off = row * 32 + (((ac0 >> 3) ^ swz(row)) << 3) + (ac0 & 7);
            *(s16x4*)&As[buf][off] = o;
        }
    };

    f32x4 acc[4][2] = {};
    {
        f32x4 av[2];
        #pragma unroll
        for (int rr = 0; rr < 2; ++rr) av[rr] = *(const f32x4*)(aSrc[rr] + ac0);
        stageB(0, 0);
        writeA(0, av);
    }
    __syncthreads();
    #pragma unroll 1
    for (int ks = 0; ks < 16; ++ks) {
        const int cur = ks & 1, nxt = cur ^ 1;
        f32x4 av[2];
        if (ks < 15) {
            const int k1 = (ks + 1) << 5;
            #pragma unroll
            for (int rr = 0; rr < 2; ++rr) av[rr] = *(const f32x4*)(aSrc[rr] + k1 + ac0);
            stageB(nxt, ks + 1);
        }
        s16x8 fb[2];
        #pragma unroll
        for (int fj = 0; fj < 2; ++fj) {
            int row = wid * 32 + fj * 16 + l15;
            fb[fj] = *(s16x8*)&Bs[cur][row * 32 + ((lg ^ swz(row)) << 3)];
        }
        #pragma unroll
        for (int fi = 0; fi < 4; ++fi) {
            int row = fi * 16 + l15;
            s16x8 fa = *(s16x8*)&As[cur][row * 32 + ((lg ^ swz(row)) << 3)];
            #pragma unroll
            for (int fj = 0; fj < 2; ++fj)
                acc[fi][fj] = MFMAB16(fa, fb[fj], acc[fi][fj]);
        }
        if (ks < 15) writeA(nxt, av);
        __syncthreads();
    }
    #pragma unroll
    for (int fi = 0; fi < 4; ++fi)
    #pragma unroll
    for (int fj = 0; fj < 2; ++fj)
    #pragma unroll
    for (int j = 0; j < 4; ++j) {
        int m = m0 + fi * 16 + lg * 4 + j;
        int n = n0 + wid * 32 + fj * 16 + l15;
        res[(size_t)m * Hn + n] = acc[fi][fj][j] + cvec[n];
    }
}

// ---------------------------------------------------------------------------
extern "C" void kernel_launch(void* const* d_in, const int* in_sizes, int n_in,
                              void* d_out, int out_size, void* d_ws, size_t ws_size,
                              hipStream_t stream)
{
    const float* query = (const float*)d_in[0];
    const float* key_  = (const float*)d_in[1];
    const float* value = (const float*)d_in[2];
    const int*   mask  = (const int*)d_in[3];
    const float* Wq = (const float*)d_in[4];
    const float* bq = (const float*)d_in[5];
    const float* Wk = (const float*)d_in[6];
    const float* bv = (const float*)d_in[9];
    const float* Wv = (const float*)d_in[8];
    const float* Wo = (const float*)d_in[10];
    const float* bo = (const float*)d_in[11];

    float* res = (float*)d_out;                       // (B,Q,H) f32
    float* scoreBase = res + (size_t)Mn * Hn;         // (B,Q,K) f32, 134 MB
    char* sc = (char*)scoreBase;                      // scratch inside score region
    constexpr size_t MB = 1u << 20;
    f16*   qM_h = (f16*)(sc + 0 * MB);                // 16 MB
    f16*   qM_l = (f16*)(sc + 16 * MB);               // 16 MB
    f16*   Kc_h = (f16*)(sc + 32 * MB);               // 16 MB
    f16*   apxE = (f16*)(sc + 48 * MB);               // 64 MB
    char*  wb   = sc + 112 * MB;
    f16*   Mt_h = (f16*)(wb);
    f16*   Mt_l = (f16*)(wb + 524288);
    f16*   Wk_h = (f16*)(wb + 2 * 524288);
    f16*   Wk_l = (f16*)(wb + 3 * 524288);
    short* Wot  = (short*)(wb + 4 * 524288);
    float* wvec = (float*)(wb + 5 * 524288);
    float* beta = (float*)(wb + 5 * 524288 + 8192);              // 64 KB
    int*   cidx = (int*)(wb + 5 * 524288 + 8192 + 65536);        // 64 KB
    float* pval = (float*)(wb + 6 * 524288);                     // 1 MB
    int*   pidx = (int*)(wb + 8 * 524288);                       // 1 MB

    int*   idxArr = (int*)d_ws;                                  // 64 KB
    int*   cnt    = (int*)d_ws + 16384;                          // 32 B
    float* cvec   = (float*)((char*)d_ws + 65600);               // 2 KB
    short* NtB    = (short*)((char*)d_ws + 67648);               // 512 KB

    prep_all<<<1033, 256, 0, stream>>>(mask, Wk, Wo, bq, bv, bo,
                                       cidx, cnt, Wk_h, Wk_l, Wot, wvec, cvec);

    gemm_split<1><<<dim3(8, 4), 256, 0, stream>>>(Wq, Wk_h, Wk_l, Mt_h, Mt_l);
    gemm_bfk0<<<dim3(8, 4), 256, 0, stream>>>(Wv, Wot, NtB);

    qm_kconv<<<5120, 256, 0, stream>>>(query, Mt_h, Mt_l, qM_h, qM_l,
                                       key_, cidx, cnt, wvec, Kc_h, beta);

    energy_approx<<<dim3(Qn / 128, 16, Bn), 256, 0, stream>>>(
        qM_h, Kc_h, beta, cnt, apxE, pval, pidx);

    refine<<<Mn / 4, 256, 0, stream>>>(
        apxE, pval, pidx, qM_h, qM_l, key_, beta, cidx, cnt, idxArr);

    tail_fused<<<1024 + Mn, 256, 0, stream>>>(value, NtB, cvec, idxArr,
                                              res, scoreBase);
}